// Round 1
// baseline (37634.241 us; speedup 1.0000x reference)
//
#include <hip/hip_runtime.h>

// Problem constants (match setup_inputs)
#define Bz  16
#define Tz  1024
#define Cz  16
#define Dz  256
#define NHz 4
#define HDz 64
#define Lz  4
#define MROWS (Bz*Tz)   // 16384
#define QB  8           // attention q-rows per block

__device__ __forceinline__ float sigmoidf_(float x){ return 1.0f/(1.0f+__expf(-x)); }

// ---------------------------------------------------------------------------
// K0: per-batch diffusion-step embedding te, FiLM gamma/beta.  grid=B, block=256
// ---------------------------------------------------------------------------
__global__ __launch_bounds__(256) void k_batch_emb(
    const int* __restrict__ t, const float* __restrict__ te_freqs,
    const float* __restrict__ W_temb, const float* __restrict__ b_temb,
    const float* __restrict__ W_film, const float* __restrict__ b_film,
    float* __restrict__ te_out, float* __restrict__ gamma_out, float* __restrict__ beta_out)
{
  int b = blockIdx.x; int j = threadIdx.x;
  __shared__ float s[256];
  __shared__ float ste[256];
  float tf = (float)t[b];
  if (j < 128){
    float targ = tf * te_freqs[j];
    s[j]     = __sinf(targ);
    s[j+128] = __cosf(targ);
  }
  __syncthreads();
  float a0=0,a1=0,a2=0,a3=0;
  #pragma unroll 8
  for (int k=0;k<256;k+=4){
    a0 = fmaf(s[k+0], W_temb[(k+0)*256+j], a0);
    a1 = fmaf(s[k+1], W_temb[(k+1)*256+j], a1);
    a2 = fmaf(s[k+2], W_temb[(k+2)*256+j], a2);
    a3 = fmaf(s[k+3], W_temb[(k+3)*256+j], a3);
  }
  float te = (a0+a1)+(a2+a3) + b_temb[j];
  te_out[b*256+j] = te;
  ste[j] = te * sigmoidf_(te);            // silu
  __syncthreads();
  float g0=0,g1=0,h0=0,h1=0;
  #pragma unroll 8
  for (int k=0;k<256;k+=2){
    float v0 = ste[k+0], v1 = ste[k+1];
    g0 = fmaf(v0, W_film[(k+0)*512+j],     g0);
    g1 = fmaf(v1, W_film[(k+1)*512+j],     g1);
    h0 = fmaf(v0, W_film[(k+0)*512+256+j], h0);
    h1 = fmaf(v1, W_film[(k+1)*512+256+j], h1);
  }
  gamma_out[b*256+j] = g0+g1 + b_film[j];
  beta_out [b*256+j] = h0+h1 + b_film[256+j];
}

// ---------------------------------------------------------------------------
// K1: H0 = sqrt(ab)*relu([x,mask]@W_enc+b) + sqrt(1-ab)*noise + te + FiLM(tm)
// grid = B*T, block = 256 (one output row per block)
// ---------------------------------------------------------------------------
__global__ __launch_bounds__(256) void k_encode(
    const float* __restrict__ x, const float* __restrict__ mask, const float* __restrict__ noise,
    const int* __restrict__ t, const float* __restrict__ alpha_bar, const float* __restrict__ ts,
    const float* __restrict__ W_enc, const float* __restrict__ b_enc,
    const float* __restrict__ th_a, const float* __restrict__ th_b, const float* __restrict__ th_freqs,
    const float* __restrict__ te, const float* __restrict__ gamma, const float* __restrict__ beta,
    float* __restrict__ H0)
{
  int bt = blockIdx.x; int b = bt >> 10;
  int j = threadIdx.x;
  __shared__ float in[32];
  if (j < 16)      in[j] = x[bt*16 + j];
  else if (j < 32) in[j] = mask[bt*16 + (j-16)];
  __syncthreads();
  float acc = 0.f;
  #pragma unroll
  for (int k=0;k<32;k++) acc = fmaf(in[k], W_enc[k*256+j], acc);
  float z = fmaxf(acc + b_enc[j], 0.f);
  float ab = alpha_bar[t[b]];
  float h = sqrtf(ab)*z + sqrtf(1.f-ab)*noise[(size_t)bt*256 + j];
  float tsv = ts[bt];
  float tm;
  if (j & 1){
    int i = (j-1) >> 1;
    tm = fmaf(tsv, th_a[i], th_b[i]);
  } else {
    int m = j >> 2;
    float ph = tsv * th_freqs[m];
    tm = ((j & 3) == 0) ? __sinf(ph) : __cosf(ph);
  }
  tm = fmaf(1.f + gamma[b*256+j], tm, beta[b*256+j]);
  H0[(size_t)bt*256 + j] = h + te[b*256+j] + tm;
}

// ---------------------------------------------------------------------------
// Generic fp32 tiled GEMM: C = A(MxK) @ W(KxN) + bias [+relu] [+residual]
// block 256 threads, 64x64 tile, BK=16, 4x4 per thread. Dims divide evenly.
// ---------------------------------------------------------------------------
template<bool RELU, bool RES>
__global__ __launch_bounds__(256) void k_gemm(
    const float* __restrict__ A, const float* __restrict__ W,
    const float* __restrict__ bias, const float* __restrict__ Rp,
    float* __restrict__ Cp, int M, int N, int K)
{
  __shared__ float As[16][68];
  __shared__ float Bs[16][64];
  int bn = blockIdx.x * 64, bm = blockIdx.y * 64;
  int tid = threadIdx.x;
  int tx = tid & 15, ty = tid >> 4;
  float acc[4][4] = {};
  for (int k0=0; k0<K; k0+=16){
    #pragma unroll
    for (int i=0;i<4;i++){
      int idx = tid + i*256;
      int m = idx >> 4, kk = idx & 15;
      As[kk][m] = A[(size_t)(bm+m)*K + k0+kk];
    }
    #pragma unroll
    for (int i=0;i<4;i++){
      int idx = tid + i*256;
      int kk = idx >> 6, n = idx & 63;
      Bs[kk][n] = W[(size_t)(k0+kk)*N + bn+n];
    }
    __syncthreads();
    #pragma unroll
    for (int kk=0;kk<16;kk++){
      float a0=As[kk][ty*4+0], a1=As[kk][ty*4+1], a2=As[kk][ty*4+2], a3=As[kk][ty*4+3];
      float b0=Bs[kk][tx*4+0], b1=Bs[kk][tx*4+1], b2=Bs[kk][tx*4+2], b3=Bs[kk][tx*4+3];
      acc[0][0]=fmaf(a0,b0,acc[0][0]); acc[0][1]=fmaf(a0,b1,acc[0][1]); acc[0][2]=fmaf(a0,b2,acc[0][2]); acc[0][3]=fmaf(a0,b3,acc[0][3]);
      acc[1][0]=fmaf(a1,b0,acc[1][0]); acc[1][1]=fmaf(a1,b1,acc[1][1]); acc[1][2]=fmaf(a1,b2,acc[1][2]); acc[1][3]=fmaf(a1,b3,acc[1][3]);
      acc[2][0]=fmaf(a2,b0,acc[2][0]); acc[2][1]=fmaf(a2,b1,acc[2][1]); acc[2][2]=fmaf(a2,b2,acc[2][2]); acc[2][3]=fmaf(a2,b3,acc[2][3]);
      acc[3][0]=fmaf(a3,b0,acc[3][0]); acc[3][1]=fmaf(a3,b1,acc[3][1]); acc[3][2]=fmaf(a3,b2,acc[3][2]); acc[3][3]=fmaf(a3,b3,acc[3][3]);
    }
    __syncthreads();
  }
  #pragma unroll
  for (int i=0;i<4;i++){
    int row = bm + ty*4 + i;
    #pragma unroll
    for (int jj=0;jj<4;jj++){
      int col = bn + tx*4 + jj;
      float v = acc[i][jj] + bias[col];
      if (RELU) v = fmaxf(v, 0.f);
      if (RES)  v += Rp[(size_t)row*N + col];
      Cp[(size_t)row*N + col] = v;
    }
  }
}

// ---------------------------------------------------------------------------
// Dot helper for the scan: out_j = sum_k vec[k]*W[k*stride + j]
// ---------------------------------------------------------------------------
__device__ __forceinline__ float dot256_col(const float* __restrict__ W,
                                            const float* __restrict__ vec, int j)
{
  float a0=0,a1=0,a2=0,a3=0;
  #pragma unroll 8
  for (int k=0;k<256;k+=4){
    a0 = fmaf(vec[k+0], W[(k+0)*256+j], a0);
    a1 = fmaf(vec[k+1], W[(k+1)*256+j], a1);
    a2 = fmaf(vec[k+2], W[(k+2)*256+j], a2);
    a3 = fmaf(vec[k+3], W[(k+3)*256+j], a3);
  }
  return (a0+a1)+(a2+a3);
}

// ---------------------------------------------------------------------------
// K3: Jump-ODE (RK4) + GRU scan. grid=B (one block per batch), block=256.
// GI (= h@Wih + bih) precomputed. Exact RK4 this round.
// ---------------------------------------------------------------------------
__global__ __launch_bounds__(256) void k_scan(
    const float* __restrict__ GI, const float* __restrict__ ts,
    const float* __restrict__ W1, const float* __restrict__ b1,
    const float* __restrict__ W2, const float* __restrict__ b2,
    const float* __restrict__ Whh, const float* __restrict__ bhh,
    float* __restrict__ Hseq)
{
  int b = blockIdx.x, j = threadIdx.x;
  __shared__ float v[256];
  __shared__ float u[256];
  const float* tsb = ts + b*Tz;
  const float* gib = GI + (size_t)b*Tz*768;
  float* hs = Hseq + (size_t)b*Tz*256;
  float bb1 = b1[j], bb2 = b2[j];
  float bhr = bhh[j], bhz = bhh[256+j], bhn = bhh[512+j];
  float hh = 0.f;
  float tprev = 0.f;
  for (int tt=0; tt<Tz; ++tt){
    float tcur = tsb[tt];
    float dt = (tt == 0) ? 0.f : (tcur - tprev);
    tprev = tcur;
    float f1,f2,f3,f4;
    v[j] = hh;                       __syncthreads();
    u[j] = tanhf(dot256_col(W1, v, j) + bb1);            __syncthreads();
    f1 = dot256_col(W2, u, j) + bb2;
    v[j] = fmaf(0.5f*dt, f1, hh);    __syncthreads();
    u[j] = tanhf(dot256_col(W1, v, j) + bb1);            __syncthreads();
    f2 = dot256_col(W2, u, j) + bb2;
    v[j] = fmaf(0.5f*dt, f2, hh);    __syncthreads();
    u[j] = tanhf(dot256_col(W1, v, j) + bb1);            __syncthreads();
    f3 = dot256_col(W2, u, j) + bb2;
    v[j] = fmaf(dt, f3, hh);         __syncthreads();
    u[j] = tanhf(dot256_col(W1, v, j) + bb1);            __syncthreads();
    f4 = dot256_col(W2, u, j) + bb2;
    float hnew = hh + (dt*(1.f/6.f))*(f1 + 2.f*f2 + 2.f*f3 + f4);
    v[j] = hnew;                     __syncthreads();
    // GRU: gh = hnew @ Whh + bhh (3 gates)
    float ar0=0,ar1=0,az0=0,az1=0,an0=0,an1=0;
    #pragma unroll 4
    for (int k=0;k<256;k+=2){
      float v0 = v[k], v1 = v[k+1];
      ar0 = fmaf(v0, Whh[(k+0)*768 + j],       ar0);
      ar1 = fmaf(v1, Whh[(k+1)*768 + j],       ar1);
      az0 = fmaf(v0, Whh[(k+0)*768 + 256 + j], az0);
      az1 = fmaf(v1, Whh[(k+1)*768 + 256 + j], az1);
      an0 = fmaf(v0, Whh[(k+0)*768 + 512 + j], an0);
      an1 = fmaf(v1, Whh[(k+1)*768 + 512 + j], an1);
    }
    float gir = gib[tt*768 + j], giz = gib[tt*768 + 256 + j], gin = gib[tt*768 + 512 + j];
    float r  = sigmoidf_(gir + ar0+ar1 + bhr);
    float zg = sigmoidf_(giz + az0+az1 + bhz);
    float n  = tanhf(gin + r*(an0+an1 + bhn));
    hh = (1.f - zg)*n + zg*hnew;
    hs[tt*256 + j] = hh;
    __syncthreads();   // protect v[] before next iteration's overwrite
  }
}

// ---------------------------------------------------------------------------
// K6: causal attention for one (b, head, q-block of 8 rows). block=256.
// Scores for the whole row kept in LDS (no online softmax needed).
// ---------------------------------------------------------------------------
__global__ __launch_bounds__(256) void k_attn(const float* __restrict__ QKV, float* __restrict__ O)
{
  int qb = blockIdx.x & (Tz/QB - 1);
  int bh = blockIdx.x / (Tz/QB);
  int b = bh >> 2, h = bh & 3;
  __shared__ float Qs[QB][65];
  __shared__ float Ks[64][65];     // reused for V in phase 2
  __shared__ float S[QB][Tz];
  int tid = threadIdx.x;
  const float* base = QKV + (size_t)b*Tz*768;
  for (int i = tid; i < QB*HDz; i += 256){
    int q = i >> 6, d = i & 63;
    Qs[q][d] = base[(size_t)(qb*QB+q)*768 + h*64 + d] * 0.125f;  // 1/sqrt(64)
  }
  __syncthreads();
  int kmax = qb*QB + QB;
  int nkt = (kmax + 63) >> 6;
  int q = tid >> 5, i0 = tid & 31;
  int qg = qb*QB + q;
  // ---- scores ----
  for (int kt=0; kt<nkt; ++kt){
    for (int i=tid;i<64*64;i+=256){
      int r=i>>6, d=i&63;
      Ks[r][d] = base[(size_t)(kt*64+r)*768 + 256 + h*64 + d];
    }
    __syncthreads();
    #pragma unroll
    for (int jj=0;jj<2;jj++){
      int k = i0 + 32*jj;
      int kg = kt*64 + k;
      float acc = 0.f;
      #pragma unroll 8
      for (int d=0; d<64; d++) acc = fmaf(Qs[q][d], Ks[k][d], acc);
      S[q][kt*64+k] = (kg <= qg) ? acc : -1e30f;
    }
    __syncthreads();
  }
  // ---- softmax over row q (32 lanes per row, same wave) ----
  int NK = nkt*64;
  float m = -1e30f;
  for (int kk=i0; kk<NK; kk+=32) m = fmaxf(m, S[q][kk]);
  #pragma unroll
  for (int o=16;o;o>>=1) m = fmaxf(m, __shfl_xor(m, o, 32));
  float sum = 0.f;
  for (int kk=i0; kk<NK; kk+=32){
    float p = __expf(S[q][kk] - m);   // masked entries -> exp(-huge) = 0
    S[q][kk] = p;
    sum += p;
  }
  #pragma unroll
  for (int o=16;o;o>>=1) sum += __shfl_xor(sum, o, 32);
  float rinv = 1.f/sum;
  // ---- PV ----
  float o0=0.f, o1=0.f;
  for (int kt=0; kt<nkt; ++kt){
    __syncthreads();
    for (int i=tid;i<64*64;i+=256){
      int r=i>>6, d=i&63;
      Ks[r][d] = base[(size_t)(kt*64+r)*768 + 512 + h*64 + d];
    }
    __syncthreads();
    int kbase = kt*64;
    #pragma unroll 8
    for (int k=0;k<64;k++){
      float p = S[q][kbase+k];
      o0 = fmaf(p, Ks[k][i0],      o0);
      o1 = fmaf(p, Ks[k][i0+32],   o1);
    }
  }
  size_t orow = ((size_t)b*Tz + qg)*256 + h*64;
  O[orow + i0]      = o0*rinv;
  O[orow + i0 + 32] = o1*rinv;
}

// ---------------------------------------------------------------------------
// LayerNorm over D=256. block=256 (4 waves -> 4 rows), grid = MROWS/4.
// FINAL variant adds Hseq and writes d_out.
// ---------------------------------------------------------------------------
template<bool FINAL>
__global__ __launch_bounds__(256) void k_ln(
    const float* __restrict__ in, const float* __restrict__ w, const float* __restrict__ bgain,
    const float* __restrict__ addv, float* __restrict__ out)
{
  int row  = blockIdx.x*4 + (threadIdx.x >> 6);
  int lane = threadIdx.x & 63;
  const float4 xv = ((const float4*)(in + (size_t)row*256))[lane];
  float s = xv.x + xv.y + xv.z + xv.w;
  #pragma unroll
  for (int o=32;o;o>>=1) s += __shfl_xor(s, o, 64);
  float mean = s * (1.f/256.f);
  float dx=xv.x-mean, dy=xv.y-mean, dz=xv.z-mean, dw=xv.w-mean;
  float qv = dx*dx + dy*dy + dz*dz + dw*dw;
  #pragma unroll
  for (int o=32;o;o>>=1) qv += __shfl_xor(qv, o, 64);
  float rstd = 1.f/sqrtf(qv*(1.f/256.f) + 1e-5f);
  const float4 wv = ((const float4*)w)[lane];
  const float4 bv = ((const float4*)bgain)[lane];
  float4 ov;
  ov.x = dx*rstd*wv.x + bv.x;
  ov.y = dy*rstd*wv.y + bv.y;
  ov.z = dz*rstd*wv.z + bv.z;
  ov.w = dw*rstd*wv.w + bv.w;
  if (FINAL){
    const float4 av = ((const float4*)(addv + (size_t)row*256))[lane];
    ov.x += av.x; ov.y += av.y; ov.z += av.z; ov.w += av.w;
  }
  ((float4*)(out + (size_t)row*256))[lane] = ov;
}

// ---------------------------------------------------------------------------
// Host launcher
// ---------------------------------------------------------------------------
extern "C" void kernel_launch(void* const* d_in, const int* in_sizes, int n_in,
                              void* d_out, int out_size, void* d_ws, size_t ws_size,
                              hipStream_t stream)
{
  const float* x         = (const float*)d_in[0];
  const int*   t         = (const int*)  d_in[1];
  const float* ts        = (const float*)d_in[2];
  const float* mask      = (const float*)d_in[3];
  const float* noise     = (const float*)d_in[4];
  // d_in[5] = n_heads (constant 4, hardcoded)
  const float* alpha_bar = (const float*)d_in[6];
  const float* W_enc     = (const float*)d_in[7];
  const float* b_enc     = (const float*)d_in[8];
  const float* te_freqs  = (const float*)d_in[9];
  const float* W_temb    = (const float*)d_in[10];
  const float* b_temb    = (const float*)d_in[11];
  const float* th_a      = (const float*)d_in[12];
  const float* th_b      = (const float*)d_in[13];
  const float* th_freqs  = (const float*)d_in[14];
  const float* W_film    = (const float*)d_in[15];
  const float* b_film    = (const float*)d_in[16];
  const float* gru_Wih   = (const float*)d_in[17];
  const float* gru_Whh   = (const float*)d_in[18];
  const float* gru_bih   = (const float*)d_in[19];
  const float* gru_bhh   = (const float*)d_in[20];
  const float* ode_W1    = (const float*)d_in[21];
  const float* ode_b1    = (const float*)d_in[22];
  const float* ode_W2    = (const float*)d_in[23];
  const float* ode_b2    = (const float*)d_in[24];
  const float* tr_Wqkv   = (const float*)d_in[25];
  const float* tr_bqkv   = (const float*)d_in[26];
  const float* tr_Wo     = (const float*)d_in[27];
  const float* tr_bo     = (const float*)d_in[28];
  const float* tr_ln1_w  = (const float*)d_in[29];
  const float* tr_ln1_b  = (const float*)d_in[30];
  const float* tr_ln2_w  = (const float*)d_in[31];
  const float* tr_ln2_b  = (const float*)d_in[32];
  const float* tr_W1     = (const float*)d_in[33];
  const float* tr_b1     = (const float*)d_in[34];
  const float* tr_W2     = (const float*)d_in[35];
  const float* tr_b2     = (const float*)d_in[36];
  const float* trn_w     = (const float*)d_in[37];
  const float* trn_b     = (const float*)d_in[38];

  // workspace layout (floats). total = 12288 + 16M + 4*4M = 33,566,720 fl = ~134.3 MB
  float* w = (float*)d_ws;
  float* te    = w;
  float* gamma = w + 4096;
  float* beta  = w + 8192;
  float* R1    = w + 12288;                 // 16M floats, multi-use region
  float* H0    = R1;                        // 4M   (dead after GI gemm)
  float* GI    = R1 + 4*1024*1024;          // 12M  (dead after scan)
  float* QKVb  = R1;                        // 12M  (per layer)
  float* F1    = R1;                        // 16M  (per layer; QKV dead by then)
  float* Hseq  = R1   + 16*1024*1024;       // 4M, persists
  float* Ht    = Hseq + 4*1024*1024;        // 4M
  float* U     = Ht   + 4*1024*1024;        // 4M
  float* O     = U    + 4*1024*1024;        // 4M

  // Phase A: embeddings + encode + GI precompute
  k_batch_emb<<<Bz, 256, 0, stream>>>(t, te_freqs, W_temb, b_temb, W_film, b_film, te, gamma, beta);
  k_encode<<<MROWS, 256, 0, stream>>>(x, mask, noise, t, alpha_bar, ts, W_enc, b_enc,
                                      th_a, th_b, th_freqs, te, gamma, beta, H0);
  k_gemm<false,false><<<dim3(768/64, MROWS/64), 256, 0, stream>>>(H0, gru_Wih, gru_bih, nullptr, GI, MROWS, 768, 256);

  // Phase B: sequential ODE+GRU scan (one block per batch)
  k_scan<<<Bz, 256, 0, stream>>>(GI, ts, ode_W1, ode_b1, ode_W2, ode_b2, gru_Whh, gru_bhh, Hseq);

  // Ht = Hseq
  hipMemcpyAsync(Ht, Hseq, (size_t)MROWS*256*sizeof(float), hipMemcpyDeviceToDevice, stream);

  // Phase C: transformer layers
  for (int l=0; l<Lz; ++l){
    k_ln<false><<<MROWS/4, 256, 0, stream>>>(Ht, tr_ln1_w + l*256, tr_ln1_b + l*256, nullptr, U);
    k_gemm<false,false><<<dim3(768/64, MROWS/64), 256, 0, stream>>>(U, tr_Wqkv + (size_t)l*256*768, tr_bqkv + l*768, nullptr, QKVb, MROWS, 768, 256);
    k_attn<<<Bz*NHz*(Tz/QB), 256, 0, stream>>>(QKVb, O);
    k_gemm<false,true><<<dim3(256/64, MROWS/64), 256, 0, stream>>>(O, tr_Wo + (size_t)l*256*256, tr_bo + l*256, Ht, Ht, MROWS, 256, 256);
    k_ln<false><<<MROWS/4, 256, 0, stream>>>(Ht, tr_ln2_w + l*256, tr_ln2_b + l*256, nullptr, U);
    k_gemm<true,false><<<dim3(1024/64, MROWS/64), 256, 0, stream>>>(U, tr_W1 + (size_t)l*256*1024, tr_b1 + l*1024, nullptr, F1, MROWS, 1024, 256);
    k_gemm<false,true><<<dim3(256/64, MROWS/64), 256, 0, stream>>>(F1, tr_W2 + (size_t)l*1024*256, tr_b2 + l*256, Ht, Ht, MROWS, 256, 1024);
  }

  // Final: out = Hseq + LN(Ht)
  k_ln<true><<<MROWS/4, 256, 0, stream>>>(Ht, trn_w, trn_b, Hseq, (float*)d_out);
}

// Round 2
// 15818.419 us; speedup vs baseline: 2.3791x; 2.3791x over previous
//
#include <hip/hip_runtime.h>

#define Bz  16
#define Tz  1024
#define Cz  16
#define Dz  256
#define NHz 4
#define HDz 64
#define Lz  4
#define MROWS (Bz*Tz)   // 16384
#define QB  8           // attention q-rows per block

__device__ __forceinline__ float sigmoidf_(float x){ return 1.0f/(1.0f+__expf(-x)); }

// v_dot2_f32_f16: acc += a.x*b.x + a.y*b.y (f16 inputs, f32 accumulate)
__device__ __forceinline__ float dot2f(uint a, uint b, float c){
  float d;
  asm("v_dot2_f32_f16 %0, %1, %2, %3" : "=v"(d) : "v"(a), "v"(b), "v"(c));
  return d;
}
// pack two floats to half2 (RTE)
__device__ __forceinline__ uint f2h2(float a, float b){
  union { _Float16 h[2]; uint u; } r;
  r.h[0] = (_Float16)a; r.h[1] = (_Float16)b;
  return r.u;
}

// ---------------------------------------------------------------------------
// Prep: convert scan weights to f16 pairs (packed along k).
// W1,W2: [256][256] -> [128][256] u32.  Whh: [256][768] -> [128][768] u32.
// ---------------------------------------------------------------------------
__global__ __launch_bounds__(256) void k_prep(
    const float* __restrict__ W1, const float* __restrict__ W2, const float* __restrict__ Whh,
    uint* __restrict__ W1h, uint* __restrict__ W2h, uint* __restrict__ Whhh)
{
  int i = blockIdx.x*256 + threadIdx.x;
  if (i < 32768){
    int kp = i >> 8, j = i & 255;
    W1h[i] = f2h2(W1[(2*kp)*256 + j], W1[(2*kp+1)*256 + j]);
  } else if (i < 65536){
    int m = i - 32768;
    int kp = m >> 8, j = m & 255;
    W2h[m] = f2h2(W2[(2*kp)*256 + j], W2[(2*kp+1)*256 + j]);
  } else if (i < 65536 + 98304){
    int m = i - 65536;
    int kp = m / 768, c = m % 768;
    Whhh[m] = f2h2(Whh[(2*kp)*768 + c], Whh[(2*kp+1)*768 + c]);
  }
}

// ---------------------------------------------------------------------------
// K0: per-batch diffusion-step embedding te, FiLM gamma/beta.  grid=B, block=256
// ---------------------------------------------------------------------------
__global__ __launch_bounds__(256) void k_batch_emb(
    const int* __restrict__ t, const float* __restrict__ te_freqs,
    const float* __restrict__ W_temb, const float* __restrict__ b_temb,
    const float* __restrict__ W_film, const float* __restrict__ b_film,
    float* __restrict__ te_out, float* __restrict__ gamma_out, float* __restrict__ beta_out)
{
  int b = blockIdx.x; int j = threadIdx.x;
  __shared__ float s[256];
  __shared__ float ste[256];
  float tf = (float)t[b];
  if (j < 128){
    float targ = tf * te_freqs[j];
    s[j]     = __sinf(targ);
    s[j+128] = __cosf(targ);
  }
  __syncthreads();
  float a0=0,a1=0,a2=0,a3=0;
  #pragma unroll 8
  for (int k=0;k<256;k+=4){
    a0 = fmaf(s[k+0], W_temb[(k+0)*256+j], a0);
    a1 = fmaf(s[k+1], W_temb[(k+1)*256+j], a1);
    a2 = fmaf(s[k+2], W_temb[(k+2)*256+j], a2);
    a3 = fmaf(s[k+3], W_temb[(k+3)*256+j], a3);
  }
  float te = (a0+a1)+(a2+a3) + b_temb[j];
  te_out[b*256+j] = te;
  ste[j] = te * sigmoidf_(te);            // silu
  __syncthreads();
  float g0=0,g1=0,h0=0,h1=0;
  #pragma unroll 8
  for (int k=0;k<256;k+=2){
    float v0 = ste[k+0], v1 = ste[k+1];
    g0 = fmaf(v0, W_film[(k+0)*512+j],     g0);
    g1 = fmaf(v1, W_film[(k+1)*512+j],     g1);
    h0 = fmaf(v0, W_film[(k+0)*512+256+j], h0);
    h1 = fmaf(v1, W_film[(k+1)*512+256+j], h1);
  }
  gamma_out[b*256+j] = g0+g1 + b_film[j];
  beta_out [b*256+j] = h0+h1 + b_film[256+j];
}

// ---------------------------------------------------------------------------
// K1: H0 = sqrt(ab)*relu([x,mask]@W_enc+b) + sqrt(1-ab)*noise + te + FiLM(tm)
// ---------------------------------------------------------------------------
__global__ __launch_bounds__(256) void k_encode(
    const float* __restrict__ x, const float* __restrict__ mask, const float* __restrict__ noise,
    const int* __restrict__ t, const float* __restrict__ alpha_bar, const float* __restrict__ ts,
    const float* __restrict__ W_enc, const float* __restrict__ b_enc,
    const float* __restrict__ th_a, const float* __restrict__ th_b, const float* __restrict__ th_freqs,
    const float* __restrict__ te, const float* __restrict__ gamma, const float* __restrict__ beta,
    float* __restrict__ H0)
{
  int bt = blockIdx.x; int b = bt >> 10;
  int j = threadIdx.x;
  __shared__ float in[32];
  if (j < 16)      in[j] = x[bt*16 + j];
  else if (j < 32) in[j] = mask[bt*16 + (j-16)];
  __syncthreads();
  float acc = 0.f;
  #pragma unroll
  for (int k=0;k<32;k++) acc = fmaf(in[k], W_enc[k*256+j], acc);
  float z = fmaxf(acc + b_enc[j], 0.f);
  float ab = alpha_bar[t[b]];
  float h = sqrtf(ab)*z + sqrtf(1.f-ab)*noise[(size_t)bt*256 + j];
  float tsv = ts[bt];
  float tm;
  if (j & 1){
    int i = (j-1) >> 1;
    tm = fmaf(tsv, th_a[i], th_b[i]);
  } else {
    int m = j >> 2;
    float ph = tsv * th_freqs[m];
    tm = ((j & 3) == 0) ? __sinf(ph) : __cosf(ph);
  }
  tm = fmaf(1.f + gamma[b*256+j], tm, beta[b*256+j]);
  H0[(size_t)bt*256 + j] = h + te[b*256+j] + tm;
}

// ---------------------------------------------------------------------------
// Generic fp32 tiled GEMM: C = A(MxK) @ W(KxN) + bias [+relu] [+residual]
// ---------------------------------------------------------------------------
template<bool RELU, bool RES>
__global__ __launch_bounds__(256) void k_gemm(
    const float* __restrict__ A, const float* __restrict__ W,
    const float* __restrict__ bias, const float* __restrict__ Rp,
    float* __restrict__ Cp, int M, int N, int K)
{
  __shared__ float As[16][68];
  __shared__ float Bs[16][64];
  int bn = blockIdx.x * 64, bm = blockIdx.y * 64;
  int tid = threadIdx.x;
  int tx = tid & 15, ty = tid >> 4;
  float acc[4][4] = {};
  for (int k0=0; k0<K; k0+=16){
    #pragma unroll
    for (int i=0;i<4;i++){
      int idx = tid + i*256;
      int m = idx >> 4, kk = idx & 15;
      As[kk][m] = A[(size_t)(bm+m)*K + k0+kk];
    }
    #pragma unroll
    for (int i=0;i<4;i++){
      int idx = tid + i*256;
      int kk = idx >> 6, n = idx & 63;
      Bs[kk][n] = W[(size_t)(k0+kk)*N + bn+n];
    }
    __syncthreads();
    #pragma unroll
    for (int kk=0;kk<16;kk++){
      float a0=As[kk][ty*4+0], a1=As[kk][ty*4+1], a2=As[kk][ty*4+2], a3=As[kk][ty*4+3];
      float b0=Bs[kk][tx*4+0], b1=Bs[kk][tx*4+1], b2=Bs[kk][tx*4+2], b3=Bs[kk][tx*4+3];
      acc[0][0]=fmaf(a0,b0,acc[0][0]); acc[0][1]=fmaf(a0,b1,acc[0][1]); acc[0][2]=fmaf(a0,b2,acc[0][2]); acc[0][3]=fmaf(a0,b3,acc[0][3]);
      acc[1][0]=fmaf(a1,b0,acc[1][0]); acc[1][1]=fmaf(a1,b1,acc[1][1]); acc[1][2]=fmaf(a1,b2,acc[1][2]); acc[1][3]=fmaf(a1,b3,acc[1][3]);
      acc[2][0]=fmaf(a2,b0,acc[2][0]); acc[2][1]=fmaf(a2,b1,acc[2][1]); acc[2][2]=fmaf(a2,b2,acc[2][2]); acc[2][3]=fmaf(a2,b3,acc[2][3]);
      acc[3][0]=fmaf(a3,b0,acc[3][0]); acc[3][1]=fmaf(a3,b1,acc[3][1]); acc[3][2]=fmaf(a3,b2,acc[3][2]); acc[3][3]=fmaf(a3,b3,acc[3][3]);
    }
    __syncthreads();
  }
  #pragma unroll
  for (int i=0;i<4;i++){
    int row = bm + ty*4 + i;
    #pragma unroll
    for (int jj=0;jj<4;jj++){
      int col = bn + tx*4 + jj;
      float v = acc[i][jj] + bias[col];
      if (RELU) v = fmaxf(v, 0.f);
      if (RES)  v += Rp[(size_t)row*N + col];
      Cp[(size_t)row*N + col] = v;
    }
  }
}

// ---------------------------------------------------------------------------
// K3: Jump-ODE (RK4) + GRU scan.  grid=B, block=512, dynamic LDS 156160 B.
// W1 (f16 pairs) LDS-resident; W2/Whh streamed f16 via uint4; v_dot2 MACs.
// Thread map: jq = tid&63 (4 output cols = jq*4..+3), q8 = tid>>6 (k-slice of 16 kp).
// ---------------------------------------------------------------------------
#define SCAN_LDS_BYTES (131072 + 24576 + 512)
__global__ __launch_bounds__(512) void k_scan(
    const uint* __restrict__ W1h, const uint* __restrict__ W2h, const uint* __restrict__ Whhh,
    const float* __restrict__ GI, const float* __restrict__ ts,
    const float* __restrict__ b1, const float* __restrict__ b2,
    const float* __restrict__ bhh, float* __restrict__ Hseq)
{
  extern __shared__ __align__(16) char smem[];
  uint*  w1  = (uint*) smem;                      // [128][256] f16 pairs (128 KB)
  float* red = (float*)(smem + 131072);           // [8][768] partials (24 KB)
  uint*  v2  = (uint*) (smem + 131072 + 24576);   // [128] current vector, f16 pairs
  int b = blockIdx.x;
  int tid = threadIdx.x;
  int j  = tid & 255;
  int jq = tid & 63;
  int q8 = tid >> 6;
  {
    const uint4* src = (const uint4*)W1h;
    uint4* dst = (uint4*)w1;
    for (int i = tid; i < 8192; i += 512) dst[i] = src[i];
  }
  const float bb1 = b1[j], bb2 = b2[j];
  const float bhr = bhh[j], bhz = bhh[256+j], bhn = bhh[512+j];
  const float* tsb = ts + b*Tz;
  const float* gib = GI + (size_t)b*Tz*768;
  float* hs = Hseq + (size_t)b*Tz*256;
  float hh = 0.f, tprev = 0.f;
  if (tid < 128) v2[tid] = 0u;
  __syncthreads();

  const uint4* w1r = (const uint4*)w1;
  const uint4* W24 = (const uint4*)W2h;
  const uint4* Wh4 = (const uint4*)Whhh;
  const int kp0 = q8*16;

  for (int tt=0; tt<Tz; ++tt){
    // prefetch (latency hidden under the 4 RK4 stages)
    float tcur = tsb[tt];
    float gir = gib[tt*768 + j];
    float giz = gib[tt*768 + 256 + j];
    float gin = gib[tt*768 + 512 + j];
    float dt = tcur - tprev; if (tt == 0) dt = 0.f;
    tprev = tcur;
    float facc = 0.f, hnew = 0.f;
    #pragma unroll 1
    for (int st=0; st<4; ++st){
      { // MV1: partials of v @ W1 (LDS)
        float a0=0,a1=0,a2=0,a3=0;
        #pragma unroll 8
        for (int kk=0; kk<16; ++kk){
          int kp = kp0 + kk;
          uint4 wv = w1r[kp*64 + jq];
          uint  vv = v2[kp];
          a0 = dot2f(wv.x, vv, a0); a1 = dot2f(wv.y, vv, a1);
          a2 = dot2f(wv.z, vv, a2); a3 = dot2f(wv.w, vv, a3);
        }
        float* rr = red + q8*768 + jq*4;
        rr[0]=a0; rr[1]=a1; rr[2]=a2; rr[3]=a3;
      }
      __syncthreads();
      { // combine -> u = tanh(.+b1) -> pack to v2
        float s = red[j];
        #pragma unroll
        for (int p=1;p<8;p++) s += red[p*768 + j];
        float u = tanhf(s + bb1);
        float nb = __shfl_xor(u, 1);
        if (tid < 256 && !(j & 1)) v2[j>>1] = f2h2(u, nb);
      }
      __syncthreads();
      { // MV2: partials of u @ W2 (global f16, L2-resident)
        float a0=0,a1=0,a2=0,a3=0;
        #pragma unroll 8
        for (int kk=0; kk<16; ++kk){
          int kp = kp0 + kk;
          uint4 wv = W24[kp*64 + jq];
          uint  vv = v2[kp];
          a0 = dot2f(wv.x, vv, a0); a1 = dot2f(wv.y, vv, a1);
          a2 = dot2f(wv.z, vv, a2); a3 = dot2f(wv.w, vv, a3);
        }
        float* rr = red + q8*768 + jq*4;
        rr[0]=a0; rr[1]=a1; rr[2]=a2; rr[3]=a3;
      }
      __syncthreads();
      { // combine -> f; advance stage vector (or hnew at st=3)
        float s = red[j];
        #pragma unroll
        for (int p=1;p<8;p++) s += red[p*768 + j];
        float f = s + bb2;
        facc += (st == 0 || st == 3) ? f : 2.f*f;
        float vnext;
        if (st == 0)      vnext = fmaf(0.5f*dt, f, hh);
        else if (st == 1) vnext = fmaf(0.5f*dt, f, hh);
        else if (st == 2) vnext = fmaf(dt, f, hh);
        else { vnext = fmaf(dt*(1.f/6.f), facc, hh); hnew = vnext; }
        float nb = __shfl_xor(vnext, 1);
        if (tid < 256 && !(j & 1)) v2[j>>1] = f2h2(vnext, nb);
      }
      __syncthreads();
    }
    { // GRU: gh = hnew @ Whh (3 gates), partials
      float ar0=0,ar1=0,ar2=0,ar3=0, az0=0,az1=0,az2=0,az3=0, an0=0,an1=0,an2=0,an3=0;
      #pragma unroll 4
      for (int kk=0; kk<16; ++kk){
        int kp = kp0 + kk;
        uint vv = v2[kp];
        uint4 wr = Wh4[kp*192 + jq];
        uint4 wz = Wh4[kp*192 + 64 + jq];
        uint4 wn = Wh4[kp*192 + 128 + jq];
        ar0=dot2f(wr.x,vv,ar0); ar1=dot2f(wr.y,vv,ar1); ar2=dot2f(wr.z,vv,ar2); ar3=dot2f(wr.w,vv,ar3);
        az0=dot2f(wz.x,vv,az0); az1=dot2f(wz.y,vv,az1); az2=dot2f(wz.z,vv,az2); az3=dot2f(wz.w,vv,az3);
        an0=dot2f(wn.x,vv,an0); an1=dot2f(wn.y,vv,an1); an2=dot2f(wn.z,vv,an2); an3=dot2f(wn.w,vv,an3);
      }
      float* rr = red + q8*768 + jq*4;
      rr[0]=ar0; rr[1]=ar1; rr[2]=ar2; rr[3]=ar3;
      rr[256]=az0; rr[257]=az1; rr[258]=az2; rr[259]=az3;
      rr[512]=an0; rr[513]=an1; rr[514]=an2; rr[515]=an3;
    }
    __syncthreads();
    { // GRU combine + state update
      float sr=0, sz=0, sn=0;
      #pragma unroll
      for (int p=0;p<8;p++){
        sr += red[p*768 + j];
        sz += red[p*768 + 256 + j];
        sn += red[p*768 + 512 + j];
      }
      float r  = sigmoidf_(gir + sr + bhr);
      float zg = sigmoidf_(giz + sz + bhz);
      float n  = tanhf(gin + r*(sn + bhn));
      hh = (1.f - zg)*n + zg*hnew;
      float nb = __shfl_xor(hh, 1);
      if (tid < 256 && !(j & 1)) v2[j>>1] = f2h2(hh, nb);
      if (tid < 256) hs[tt*256 + j] = hh;
    }
    __syncthreads();
  }
}

// ---------------------------------------------------------------------------
// K6: causal attention, one (b,h,q-block of 8).  f16-dot2 scores, float4 PV.
// ---------------------------------------------------------------------------
__global__ __launch_bounds__(256) void k_attn(const float* __restrict__ QKV, float* __restrict__ O)
{
  int qb = blockIdx.x & (Tz/QB - 1);
  int bh = blockIdx.x / (Tz/QB);
  int b = bh >> 2, h = bh & 3;
  __shared__ uint Q2[QB][32];                 // q rows, f16 pairs along d
  __shared__ float S[QB][Tz];                 // 32 KB
  __shared__ __align__(16) char kvbuf[64*68*4]; // union: K2 [64][33] u32 | Vs [64][68] f32
  __shared__ float rs[QB];
  uint  (*K2)[33] = (uint(*)[33])kvbuf;
  float (*Vs)[68] = (float(*)[68])kvbuf;
  int tid = threadIdx.x;
  const float* base = QKV + (size_t)b*Tz*768;
  for (int i = tid; i < QB*16; i += 256){
    int q = i >> 4, c = i & 15;
    const float4 v = *(const float4*)&base[(size_t)(qb*QB+q)*768 + h*64 + c*4];
    Q2[q][c*2]   = f2h2(v.x*0.125f, v.y*0.125f);
    Q2[q][c*2+1] = f2h2(v.z*0.125f, v.w*0.125f);
  }
  __syncthreads();
  int kmax = qb*QB + QB;
  int nkt = (kmax + 63) >> 6;
  int q = tid >> 5, i0 = tid & 31;
  int qg = qb*QB + q;
  // ---- scores (f16 dot2) ----
  for (int kt=0; kt<nkt; ++kt){
    for (int i=tid; i<64*16; i+=256){
      int r=i>>4, c=i&15;
      const float4 v = *(const float4*)&base[(size_t)(kt*64+r)*768 + 256 + h*64 + c*4];
      K2[r][c*2]   = f2h2(v.x, v.y);
      K2[r][c*2+1] = f2h2(v.z, v.w);
    }
    __syncthreads();
    float a0=0.f, a1=0.f;
    #pragma unroll 8
    for (int dp=0; dp<32; ++dp){
      uint qv = Q2[q][dp];
      a0 = dot2f(K2[i0][dp],    qv, a0);
      a1 = dot2f(K2[i0+32][dp], qv, a1);
    }
    int k0g = kt*64 + i0, k1g = k0g + 32;
    S[q][kt*64+i0]    = (k0g <= qg) ? a0 : -1e30f;
    S[q][kt*64+i0+32] = (k1g <= qg) ? a1 : -1e30f;
    __syncthreads();
  }
  // ---- softmax (32 lanes per row) ----
  int NK = nkt*64;
  float m = -1e30f;
  for (int kk=i0; kk<NK; kk+=32) m = fmaxf(m, S[q][kk]);
  #pragma unroll
  for (int o=16;o;o>>=1) m = fmaxf(m, __shfl_xor(m, o, 32));
  float sum = 0.f;
  for (int kk=i0; kk<NK; kk+=32){
    float p = __expf(S[q][kk] - m);
    S[q][kk] = p;
    sum += p;
  }
  #pragma unroll
  for (int o=16;o;o>>=1) sum += __shfl_xor(sum, o, 32);
  if (i0 == 0) rs[q] = 1.f/sum;
  // ---- PV: (q, ks=k-parity, dq=d-quad) ----
  int dq = tid & 15;
  int ks = (tid >> 4) & 1;
  float o0=0,o1=0,o2=0,o3=0;
  for (int kt=0; kt<nkt; ++kt){
    __syncthreads();
    for (int i=tid; i<64*16; i+=256){
      int r=i>>4, c=i&15;
      const float4 v = *(const float4*)&base[(size_t)(kt*64+r)*768 + 512 + h*64 + c*4];
      *(float4*)&Vs[r][c*4] = v;
    }
    __syncthreads();
    int kbase = kt*64;
    #pragma unroll 8
    for (int kk=ks; kk<64; kk+=2){
      float p = S[q][kbase+kk];
      const float4 vv = *(const float4*)&Vs[kk][dq*4];
      o0=fmaf(p,vv.x,o0); o1=fmaf(p,vv.y,o1); o2=fmaf(p,vv.z,o2); o3=fmaf(p,vv.w,o3);
    }
  }
  o0 += __shfl_xor(o0, 16); o1 += __shfl_xor(o1, 16);
  o2 += __shfl_xor(o2, 16); o3 += __shfl_xor(o3, 16);
  if (!(tid & 16)){
    float r = rs[q];
    size_t orow = ((size_t)b*Tz + qg)*256 + h*64 + dq*4;
    float4 ov = {o0*r, o1*r, o2*r, o3*r};
    *(float4*)&O[orow] = ov;
  }
}

// ---------------------------------------------------------------------------
// LayerNorm over D=256.
// ---------------------------------------------------------------------------
template<bool FINAL>
__global__ __launch_bounds__(256) void k_ln(
    const float* __restrict__ in, const float* __restrict__ w, const float* __restrict__ bgain,
    const float* __restrict__ addv, float* __restrict__ out)
{
  int row  = blockIdx.x*4 + (threadIdx.x >> 6);
  int lane = threadIdx.x & 63;
  const float4 xv = ((const float4*)(in + (size_t)row*256))[lane];
  float s = xv.x + xv.y + xv.z + xv.w;
  #pragma unroll
  for (int o=32;o;o>>=1) s += __shfl_xor(s, o, 64);
  float mean = s * (1.f/256.f);
  float dx=xv.x-mean, dy=xv.y-mean, dz=xv.z-mean, dw=xv.w-mean;
  float qv = dx*dx + dy*dy + dz*dz + dw*dw;
  #pragma unroll
  for (int o=32;o;o>>=1) qv += __shfl_xor(qv, o, 64);
  float rstd = 1.f/sqrtf(qv*(1.f/256.f) + 1e-5f);
  const float4 wv = ((const float4*)w)[lane];
  const float4 bv = ((const float4*)bgain)[lane];
  float4 ov;
  ov.x = dx*rstd*wv.x + bv.x;
  ov.y = dy*rstd*wv.y + bv.y;
  ov.z = dz*rstd*wv.z + bv.z;
  ov.w = dw*rstd*wv.w + bv.w;
  if (FINAL){
    const float4 av = ((const float4*)(addv + (size_t)row*256))[lane];
    ov.x += av.x; ov.y += av.y; ov.z += av.z; ov.w += av.w;
  }
  ((float4*)(out + (size_t)row*256))[lane] = ov;
}

// ---------------------------------------------------------------------------
extern "C" void kernel_launch(void* const* d_in, const int* in_sizes, int n_in,
                              void* d_out, int out_size, void* d_ws, size_t ws_size,
                              hipStream_t stream)
{
  const float* x         = (const float*)d_in[0];
  const int*   t         = (const int*)  d_in[1];
  const float* ts        = (const float*)d_in[2];
  const float* mask      = (const float*)d_in[3];
  const float* noise     = (const float*)d_in[4];
  const float* alpha_bar = (const float*)d_in[6];
  const float* W_enc     = (const float*)d_in[7];
  const float* b_enc     = (const float*)d_in[8];
  const float* te_freqs  = (const float*)d_in[9];
  const float* W_temb    = (const float*)d_in[10];
  const float* b_temb    = (const float*)d_in[11];
  const float* th_a      = (const float*)d_in[12];
  const float* th_b      = (const float*)d_in[13];
  const float* th_freqs  = (const float*)d_in[14];
  const float* W_film    = (const float*)d_in[15];
  const float* b_film    = (const float*)d_in[16];
  const float* gru_Wih   = (const float*)d_in[17];
  const float* gru_Whh   = (const float*)d_in[18];
  const float* gru_bih   = (const float*)d_in[19];
  const float* gru_bhh   = (const float*)d_in[20];
  const float* ode_W1    = (const float*)d_in[21];
  const float* ode_b1    = (const float*)d_in[22];
  const float* ode_W2    = (const float*)d_in[23];
  const float* ode_b2    = (const float*)d_in[24];
  const float* tr_Wqkv   = (const float*)d_in[25];
  const float* tr_bqkv   = (const float*)d_in[26];
  const float* tr_Wo     = (const float*)d_in[27];
  const float* tr_bo     = (const float*)d_in[28];
  const float* tr_ln1_w  = (const float*)d_in[29];
  const float* tr_ln1_b  = (const float*)d_in[30];
  const float* tr_ln2_w  = (const float*)d_in[31];
  const float* tr_ln2_b  = (const float*)d_in[32];
  const float* tr_W1     = (const float*)d_in[33];
  const float* tr_b1     = (const float*)d_in[34];
  const float* tr_W2     = (const float*)d_in[35];
  const float* tr_b2     = (const float*)d_in[36];
  const float* trn_w     = (const float*)d_in[37];
  const float* trn_b     = (const float*)d_in[38];

  float* w = (float*)d_ws;
  float* te    = w;
  float* gamma = w + 4096;
  float* beta  = w + 8192;
  float* R1    = w + 12288;                 // 16M floats, multi-use
  float* H0    = R1;
  float* GI    = R1 + 4*1024*1024;
  float* QKVb  = R1;
  float* F1    = R1;
  float* Hseq  = R1   + 16*1024*1024;
  float* Ht    = Hseq + 4*1024*1024;
  float* U     = Ht   + 4*1024*1024;
  float* O     = U    + 4*1024*1024;
  uint*  W1h   = (uint*)(O + 4*1024*1024);  // 32768 u32
  uint*  W2h   = W1h + 32768;               // 32768 u32
  uint*  Whhh  = W2h + 32768;               // 98304 u32

  // Phase A
  k_prep<<<640, 256, 0, stream>>>(ode_W1, ode_W2, gru_Whh, W1h, W2h, Whhh);
  k_batch_emb<<<Bz, 256, 0, stream>>>(t, te_freqs, W_temb, b_temb, W_film, b_film, te, gamma, beta);
  k_encode<<<MROWS, 256, 0, stream>>>(x, mask, noise, t, alpha_bar, ts, W_enc, b_enc,
                                      th_a, th_b, th_freqs, te, gamma, beta, H0);
  k_gemm<false,false><<<dim3(768/64, MROWS/64), 256, 0, stream>>>(H0, gru_Wih, gru_bih, nullptr, GI, MROWS, 768, 256);

  // Phase B: scan (156 KB dynamic LDS)
  hipFuncSetAttribute((const void*)k_scan, hipFuncAttributeMaxDynamicSharedMemorySize, SCAN_LDS_BYTES);
  k_scan<<<Bz, 512, SCAN_LDS_BYTES, stream>>>(W1h, W2h, Whhh, GI, ts, ode_b1, ode_b2, gru_bhh, Hseq);

  hipMemcpyAsync(Ht, Hseq, (size_t)MROWS*256*sizeof(float), hipMemcpyDeviceToDevice, stream);

  // Phase C
  for (int l=0; l<Lz; ++l){
    k_ln<false><<<MROWS/4, 256, 0, stream>>>(Ht, tr_ln1_w + l*256, tr_ln1_b + l*256, nullptr, U);
    k_gemm<false,false><<<dim3(768/64, MROWS/64), 256, 0, stream>>>(U, tr_Wqkv + (size_t)l*256*768, tr_bqkv + l*768, nullptr, QKVb, MROWS, 768, 256);
    k_attn<<<Bz*NHz*(Tz/QB), 256, 0, stream>>>(QKVb, O);
    k_gemm<false,true><<<dim3(256/64, MROWS/64), 256, 0, stream>>>(O, tr_Wo + (size_t)l*256*256, tr_bo + l*256, Ht, Ht, MROWS, 256, 256);
    k_ln<false><<<MROWS/4, 256, 0, stream>>>(Ht, tr_ln2_w + l*256, tr_ln2_b + l*256, nullptr, U);
    k_gemm<true,false><<<dim3(1024/64, MROWS/64), 256, 0, stream>>>(U, tr_W1 + (size_t)l*256*1024, tr_b1 + l*1024, nullptr, F1, MROWS, 1024, 256);
    k_gemm<false,true><<<dim3(256/64, MROWS/64), 256, 0, stream>>>(F1, tr_W2 + (size_t)l*1024*256, tr_b2 + l*256, Ht, Ht, MROWS, 256, 1024);
  }

  k_ln<true><<<MROWS/4, 256, 0, stream>>>(Ht, trn_w, trn_b, Hseq, (float*)d_out);
}